// Round 8
// baseline (107.690 us; speedup 1.0000x reference)
//
#include <hip/hip_runtime.h>

// Problem: B=4, N=384, DX=2, DR=128, H=128, DOUT=64
// out[b,n,m,o] = relu( (x_ctx[b,n]-x_ctx[b,m]) @ W1[0:2] + r[b] @ W1[2:130] + b1 ) @ W2 + b2
//
// Round-8: R7 minus NT stores, minus sched_barrier(0). Clean test of the
// no-drain barrier. R7's 72us == 151MB at 2.1 TB/s == NT bypassing L2/L3
// (NT was the regression, not the barrier). Here:
//   - LDS-publish barrier = s_waitcnt lgkmcnt(0) + raw s_barrier ONLY ->
//     global stores stay in flight across tiles (no vmcnt(0) drain that
//     __syncthreads would emit).
//   - Plain cached stores, 4 x 2KB fully-contiguous bursts per super-iter.
//   - unroll 2 -> distinct rv register banks across consecutive rounds ->
//     WAR waitcnt sits at vmcnt(~4) instead of 0.
//   - Little's law: ~23KB/CU outstanding needed for 6.6 TB/s; this gives
//     ~4KB x 12 waves ~ 48KB continuously.
// Ping-pong safety (1 lgkm-barrier per round, 2-deep tbuf):
//   wave A writes tbuf[s] in round tp+2 only after passing BAR(tp+1);
//   every wave B arrived at BAR(tp+1) only after its lgkmcnt(0) retired
//   its round-tp ds_reads of tbuf[s]. Stores read rv REGISTERS (not tbuf),
//   so in-flight stores are unaffected by tbuf overwrite; rv reg WAR is
//   guarded by the compiler's counted vmcnt.

typedef __attribute__((ext_vector_type(8))) __bf16 bf16x8;
typedef __attribute__((ext_vector_type(4))) float f32x4;
typedef __attribute__((ext_vector_type(2))) float f32x2;

#define B_    4
#define N_    384
#define H_    128
#define DOUT_ 64

__global__ __launch_bounds__(128, 3) void te_fused(
    const float* __restrict__ r, const float* __restrict__ xctx,
    const float* __restrict__ W1, const float* __restrict__ b1,
    const float* __restrict__ W2, const float* __restrict__ b2,
    float* __restrict__ out)
{
    __shared__ __align__(16) float xs[N_ * 2];          // 3 KB   x_ctx[b]
    __shared__ __align__(16) float cs[H_];              // 0.5 KB c[b,:]
    __shared__ __align__(16) float tbuf[2][2][16][64];  // 16 KB  dbuf x 2 m-tiles

    const int tid  = threadIdx.x;
    const int w    = tid >> 6, lane = tid & 63;
    const int g    = lane >> 4, rl = lane & 15;

    const int bid = blockIdx.x;
    const int b = bid / N_, n = bid - b * N_;

    // ---- c[k] = b1[k] + sum_d r[b,d] * W1[2+d,k]  (thread k = tid) ----
    {
        float acc = b1[tid];
        const float* wc = W1 + 2 * H_ + tid;
        const float* rb = r + b * 128;
        #pragma unroll 8
        for (int d = 0; d < 128; ++d) acc = fmaf(rb[d], wc[d * H_], acc);
        cs[tid] = acc;
    }
    // ---- stage x_ctx[b]: 768 floats = 192 f32x4 ----
    {
        const float* xb = xctx + b * (N_ * 2);
        *reinterpret_cast<f32x4*>(&xs[tid * 4]) =
            *reinterpret_cast<const f32x4*>(xb + tid * 4);
        if (tid < 64)
            *reinterpret_cast<f32x4*>(&xs[(128 + tid) * 4]) =
                *reinterpret_cast<const f32x4*>(xb + (128 + tid) * 4);
    }

    // ---- W2^T fragments for this wave's o-slice [32w, 32w+32) ----
    // A-frag row = o_within_tile = rl; elem jj -> kk = ks*32+(jj>=4)*16+g*4+(jj&3)
    bf16x8 w2f[2][4];
    #pragma unroll
    for (int ot = 0; ot < 2; ++ot) {
        const float* wp = W2 + w * 32 + ot * 16 + rl;   // + kk*64
        #pragma unroll
        for (int ks = 0; ks < 4; ++ks)
            #pragma unroll
            for (int jj = 0; jj < 8; ++jj) {
                const int kk = ks * 32 + ((jj >> 2) << 4) + (g << 2) + (jj & 3);
                w2f[ot][ks][jj] = (__bf16)wp[kk * DOUT_];
            }
    }

    // ---- W1 row fragments + b2 fragments ----
    f32x4 w1a[4][2], w1b[4][2], cf[4][2], b2f[2];
    #pragma unroll
    for (int ks = 0; ks < 4; ++ks)
        #pragma unroll
        for (int hh = 0; hh < 2; ++hh) {
            const int kk = ks * 32 + hh * 16 + (g << 2);
            w1a[ks][hh] = *reinterpret_cast<const f32x4*>(W1 + kk);
            w1b[ks][hh] = *reinterpret_cast<const f32x4*>(W1 + H_ + kk);
        }
    #pragma unroll
    for (int ot = 0; ot < 2; ++ot)
        b2f[ot] = *reinterpret_cast<const f32x4*>(b2 + w * 32 + ot * 16 + (g << 2));

    __syncthreads();   // xs + cs ready (full sync ok: no stores issued yet)

    #pragma unroll
    for (int ks = 0; ks < 4; ++ks)
        #pragma unroll
        for (int hh = 0; hh < 2; ++hh)
            cf[ks][hh] = *reinterpret_cast<const f32x4*>(&cs[ks * 32 + hh * 16 + (g << 2)]);

    const float x0n = xs[2 * n], x1n = xs[2 * n + 1];
    float* const outn = out + ((size_t)(b * N_ + n)) * N_ * DOUT_;
    const int ob2 = tid & 15;     // read-side 16B o-block
    const int mr0 = tid >> 4;     // read-side row 0..7

    // ---- main loop: 12 super-iters x 2 m-tiles of 16 ----
    #pragma unroll 2
    for (int tp = 0; tp < 12; ++tp) {
        const int s = tp & 1;

        #pragma unroll
        for (int half = 0; half < 2; ++half) {
            const int m = tp * 32 + half * 16 + rl;
            const f32x2 xp = *reinterpret_cast<const f32x2*>(&xs[2 * m]);
            const float dx0 = x0n - xp[0], dx1 = x1n - xp[1];

            bf16x8 hf[4];
            #pragma unroll
            for (int ks = 0; ks < 4; ++ks)
                #pragma unroll
                for (int hh = 0; hh < 2; ++hh)
                    #pragma unroll
                    for (int j = 0; j < 4; ++j) {
                        float hp = fmaf(dx1, w1b[ks][hh][j],
                                   fmaf(dx0, w1a[ks][hh][j], cf[ks][hh][j]));
                        hf[ks][hh * 4 + j] = (__bf16)(hp > 0.f ? hp : 0.f);
                    }

            f32x4 acc0 = b2f[0], acc1 = b2f[1];
            #pragma unroll
            for (int ks = 0; ks < 4; ++ks) {
                acc0 = __builtin_amdgcn_mfma_f32_16x16x32_bf16(w2f[0][ks], hf[ks], acc0, 0, 0, 0);
                acc1 = __builtin_amdgcn_mfma_f32_16x16x32_bf16(w2f[1][ks], hf[ks], acc1, 0, 0, 0);
            }

            // transpose-write: D col=rl=m, rows o = w*32+ot*16+g*4+reg.
            // 16B-block index ob = w*8+ot*4+g, swizzled ob^rl (uniform banks).
            {
                const int ob0 = (w << 3) | g;
                *reinterpret_cast<f32x4*>(&tbuf[s][half][rl][(ob0 ^ rl) << 2]) = acc0;
                const int ob1 = (w << 3) | 4 | g;
                *reinterpret_cast<f32x4*>(&tbuf[s][half][rl][(ob1 ^ rl) << 2]) = acc1;
            }
        }

        // LDS-publish barrier WITHOUT vmcnt drain: stores stay in flight.
        asm volatile("s_waitcnt lgkmcnt(0)" ::: "memory");
        __builtin_amdgcn_s_barrier();

        // cooperative read + store: 4 passes x 2KB fully contiguous (cached)
        float* const onp = outn + (size_t)(tp * 32) * DOUT_;
        #pragma unroll
        for (int p = 0; p < 4; ++p) {
            const int sub = p >> 1;
            const int mr  = mr0 + ((p & 1) << 3);
            f32x4 rv = *reinterpret_cast<const f32x4*>(&tbuf[s][sub][mr][(ob2 ^ mr) << 2]);
            *reinterpret_cast<f32x4*>(onp + (size_t)(sub * 16 + mr) * DOUT_ + (ob2 << 2)) = rv;
        }
    }
}

extern "C" void kernel_launch(void* const* d_in, const int* in_sizes, int n_in,
                              void* d_out, int out_size, void* d_ws, size_t ws_size,
                              hipStream_t stream)
{
    const float* r    = (const float*)d_in[0];
    const float* xctx = (const float*)d_in[1];
    // d_in[2] = y_ctx (unused), d_in[3] = x_trg (unused)
    const float* W1 = (const float*)d_in[4];
    const float* b1 = (const float*)d_in[5];
    const float* W2 = (const float*)d_in[6];
    const float* b2 = (const float*)d_in[7];
    float* out = (float*)d_out;

    hipLaunchKernelGGL(te_fused, dim3(B_ * N_), dim3(128), 0, stream,
                       r, xctx, W1, b1, W2, b2, out);
}

// Round 9
// 40.586 us; speedup vs baseline: 2.6534x; 2.6534x over previous
//
#include <hip/hip_runtime.h>

// Problem: B=4, N=384, DX=2, DR=128, H=128, DOUT=64
// out[b,n,m,o] = relu( (x_ctx[b,n]-x_ctx[b,m]) @ W1[0:2] + r[b] @ W1[2:130] + b1 ) @ W2 + b2
//
// Round-9: exact Round-4 kernel (best: 40.56us) + FULL unroll of the 6-iter
// m-loop. Unified model of R1-R8: each wave's store->register-WAR distance
// vs store latency sets effective write BW. R4's unroll-2 put the WAR wait
// at ~1 body (~700cy) < loaded store latency (~1300-2000cy) -> ~40% stall
// -> 4.0 TB/s. Full unroll gives every body distinct rowv/acc banks: reuse
// distance >= 3-5 bodies (>2100cy) -> WAR waits should be satisfied on
// arrival -> approach fillBuffer's 6.7 TB/s.
// Evidence backing the other choices (kept from R4):
//   - contiguous 1KB-per-wave bursts via per-wave LDS transpose (R6: direct
//     64B segments = 3.0 TB/s; R8: scalarized sectors = 1.4 TB/s + RFO).
//   - plain cached stores (R7: NT = 2.1 TB/s, bypasses L2 write-combine).
//   - no inline asm anywhere near stores (R8: "memory"-clobber asm barrier
//     broke codegen -> 167MB of RFO fetches).
//   - __launch_bounds__(256,2): 256-VGPR budget, no spill at ~220 peak.

typedef __attribute__((ext_vector_type(8))) __bf16 bf16x8;
typedef __attribute__((ext_vector_type(4))) float f32x4;

#define B_    4
#define N_    384
#define H_    128
#define DOUT_ 64

__global__ __launch_bounds__(256, 2) void te_fused(
    const float* __restrict__ r, const float* __restrict__ xctx,
    const float* __restrict__ W1, const float* __restrict__ b1,
    const float* __restrict__ W2, const float* __restrict__ b2,
    float* __restrict__ out)
{
    __shared__ __align__(16) float xs[N_ * 2];        // 3 KB  x_ctx[b]
    __shared__ __align__(16) float cpart[2][H_];      // 1 KB  c partials
    __shared__ __align__(16) float tbuf[4][16][64];   // 16 KB per-wave transpose

    const int tid  = threadIdx.x;
    const int wave = tid >> 6, lane = tid & 63;
    const int g = lane >> 4, rl = lane & 15;

    const int bid = blockIdx.x;
    const int b = bid / N_, n = bid - b * N_;

    // ---- prologue: c partial reduction (all 256 threads) ----
    {
        const int k = tid & 127, dh = tid >> 7;
        float acc = dh ? 0.f : b1[k];
        const float* wc = W1 + (2 + dh * 64) * H_ + k;
        const float* rb = r + b * 128 + dh * 64;
        #pragma unroll 8
        for (int d = 0; d < 64; ++d) acc = fmaf(rb[d], wc[d * H_], acc);
        cpart[dh][k] = acc;
    }
    // ---- stage x_ctx[b] (192 threads x 16 B) ----
    if (tid < 192)
        *reinterpret_cast<f32x4*>(&xs[tid * 4]) =
            *reinterpret_cast<const f32x4*>(xctx + b * (N_ * 2) + tid * 4);

    // ---- W2^T fragments: w2f[rt][ks][jj] = bf16(W2[kk][rt*16+rl]),
    //      kk = ks*32 + (jj>=4)*16 + g*4 + (jj&3)  (scalar gathers, L2-hit) ----
    bf16x8 w2f[4][4];
    #pragma unroll
    for (int rt = 0; rt < 4; ++rt) {
        const float* wp = W2 + rt * 16 + rl;   // + kk*64
        #pragma unroll
        for (int ks = 0; ks < 4; ++ks)
            #pragma unroll
            for (int jj = 0; jj < 8; ++jj) {
                const int kk = ks * 32 + ((jj >> 2) << 4) + (g << 2) + (jj & 3);
                w2f[rt][ks][jj] = (__bf16)wp[kk * DOUT_];
            }
    }

    // ---- W1 row-0/row-1 fragments + b2 fragments ----
    f32x4 w1a[4][2], w1b[4][2], cf[4][2], b2f[4];
    #pragma unroll
    for (int ks = 0; ks < 4; ++ks)
        #pragma unroll
        for (int hh = 0; hh < 2; ++hh) {
            const int kk = ks * 32 + hh * 16 + (g << 2);
            w1a[ks][hh] = *reinterpret_cast<const f32x4*>(W1 + kk);
            w1b[ks][hh] = *reinterpret_cast<const f32x4*>(W1 + H_ + kk);
        }
    #pragma unroll
    for (int rt = 0; rt < 4; ++rt)
        b2f[rt] = *reinterpret_cast<const f32x4*>(b2 + rt * 16 + (g << 2));

    __syncthreads();   // xs + cpart ready (only barrier in the kernel)

    // ---- c fragments ----
    #pragma unroll
    for (int ks = 0; ks < 4; ++ks)
        #pragma unroll
        for (int hh = 0; hh < 2; ++hh) {
            const int kk = ks * 32 + hh * 16 + (g << 2);
            cf[ks][hh] = *reinterpret_cast<const f32x4*>(&cpart[0][kk]) +
                         *reinterpret_cast<const f32x4*>(&cpart[1][kk]);
        }

    const float x0n = xs[2 * n], x1n = xs[2 * n + 1];
    float* tb = &tbuf[wave][0][0];
    const int cb2 = lane & 15;
    float* const outn = out + ((size_t)(b * N_ + n)) * N_ * DOUT_;

    // ---- main loop: wave w covers m in [w*96, w*96+96), 6 tiles of 16.
    // FULL unroll: distinct rowv/acc register banks per body -> store-WAR
    // reuse distance spans several bodies -> stores stay in flight.
    #pragma unroll
    for (int t = 0; t < 6; ++t) {
        const int mbase = wave * 96 + t * 16;
        const int m = mbase + rl;
        const float dx0 = x0n - xs[2 * m];
        const float dx1 = x1n - xs[2 * m + 1];

        bf16x8 hf[4];
        #pragma unroll
        for (int ks = 0; ks < 4; ++ks)
            #pragma unroll
            for (int hh = 0; hh < 2; ++hh)
                #pragma unroll
                for (int j = 0; j < 4; ++j) {
                    float hp = fmaf(dx1, w1b[ks][hh][j],
                               fmaf(dx0, w1a[ks][hh][j], cf[ks][hh][j]));
                    hf[ks][hh * 4 + j] = (__bf16)(hp > 0.f ? hp : 0.f);
                }

        f32x4 acc[4];
        #pragma unroll
        for (int rt = 0; rt < 4; ++rt) acc[rt] = b2f[rt];
        #pragma unroll
        for (int ks = 0; ks < 4; ++ks)
            #pragma unroll
            for (int rt = 0; rt < 4; ++rt)
                acc[rt] = __builtin_amdgcn_mfma_f32_16x16x32_bf16(w2f[rt][ks], hf[ks], acc[rt], 0, 0, 0);

        // per-wave LDS transpose (XOR block swizzle) -> 4 x 1KB contiguous stores
        #pragma unroll
        for (int rt = 0; rt < 4; ++rt) {
            const int cblk = ((rt << 2) | g) ^ rl;
            *reinterpret_cast<f32x4*>(tb + (rl << 6) + (cblk << 2)) = acc[rt];
        }
        float* onp = outn + (size_t)mbase * DOUT_;
        #pragma unroll
        for (int q = 0; q < 4; ++q) {
            const int mm = (lane >> 4) | (q << 2);
            f32x4 rowv = *reinterpret_cast<const f32x4*>(tb + (mm << 6) + ((cb2 ^ mm) << 2));
            *reinterpret_cast<f32x4*>(onp + mm * DOUT_ + (cb2 << 2)) = rowv;
        }
    }
}

extern "C" void kernel_launch(void* const* d_in, const int* in_sizes, int n_in,
                              void* d_out, int out_size, void* d_ws, size_t ws_size,
                              hipStream_t stream)
{
    const float* r    = (const float*)d_in[0];
    const float* xctx = (const float*)d_in[1];
    // d_in[2] = y_ctx (unused), d_in[3] = x_trg (unused)
    const float* W1 = (const float*)d_in[4];
    const float* b1 = (const float*)d_in[5];
    const float* W2 = (const float*)d_in[6];
    const float* b2 = (const float*)d_in[7];
    float* out = (float*)d_out;

    hipLaunchKernelGGL(te_fused, dim3(B_ * N_), dim3(256), 0, stream,
                       r, xctx, W1, b1, W2, b2, out);
}